// Round 13
// baseline (312.161 us; speedup 1.0000x reference)
//
#include <hip/hip_runtime.h>
#include <hip/hip_bf16.h>

// Cabasc: B=64, S=512, Ta=8, D=768
// Round 15: gemm tile 128x64 (BK=64, dbuf 48KB) -> 3 blocks/CU (12 waves/CU).
//   Mechanism: cross-block overlap hides the 2-phase stage+barrier stall
//   (m97/m114 evidence: 32KB-LDS 3-4 blocks/CU = 874 TF vs our 64KB 2/CU 609).
//   Same 128B row layout, same XOR swizzle, same __syncthreads 2-phase sync —
//   constants-only change. sc_part -> 24 partials (et<12 x wn<2); softmax
//   folds 24. All other kernels byte-frozen from R12 (303.5us, passed).

#define NB 64
#define NS 512
#define ND 768
#define NTA 8

typedef __attribute__((ext_vector_type(8))) __bf16 bf16x8;
typedef __attribute__((ext_vector_type(4))) float f32x4;

// ---- workspace layout (bytes), all buffers fully written before read ----
#define OFF_PVS 0u              // part_vs  [32][NB][ND] f32 = 6291456
#define OFF_PVTS 6291456u       // part_vts [16][NB][ND] f32 = 3145728
#define OFF_PCTX 9437184u       // ctx_part [4][NB][ND] f32  = 786432
#define OFF_CTX 10223616u       // ctx      [NB][ND] f32     = 196608 (b1 folded)
#define OFF_PU 10420224u        // u_part   [4][NB][ND] f32  = 786432
#define OFF_PSC 11206656u       // sc_part  [24][NB][NS] f32 = 3145728
#define OFF_ALPHA 14352384u     // alpha    [NB][NS] f32     = 131072
#define OFF_VS 14483456u        // v_s  NB*ND f32 = 196608
#define OFF_VA 14680064u        // v_a  NB*ND f32 = 196608
#define OFF_LENS 14876672u      // mlenf[64] | inv_mlen[64] | inv_alen[64]
#define OFF_W1MT 14877696u      // ND*ND bf16 = 1179648
#define OFF_MP 16057344u        // NB*NS*ND bf16 = 50331648 (total ~66.4 MB)

__device__ __forceinline__ float fast_tanh(float x) {
  x = fminf(fmaxf(x, -15.f), 15.f);
  float t = __expf(2.f * x);
  return __fdividef(t - 1.f, t + 1.f);
}

__device__ __forceinline__ unsigned bfpack2(float a, float b) {
  unsigned ua = __float_as_uint(a), ub = __float_as_uint(b);
  ua = (ua + 0x7FFFu + ((ua >> 16) & 1u)) >> 16;
  ub = (ub + 0x7FFFu + ((ub >> 16) & 1u)) >> 16;
  return ua | (ub << 16);
}

__device__ __forceinline__ unsigned short bf16b(float f) {
  unsigned u = __float_as_uint(f);
  u = (u + 0x7FFFu + ((u >> 16) & 1u)) >> 16;
  return (unsigned short)u;
}

__device__ __forceinline__ void async_copy16(const void* g, void* l) {
  __builtin_amdgcn_global_load_lds(
      (const __attribute__((address_space(1))) void*)g,
      (__attribute__((address_space(3))) void*)l, 16, 0, 0);
}

// ---------- fused: W1_m transpose (blocks 0..575) + lens/v_a prep (blocks 576..639) ----------
__global__ __launch_bounds__(256) void k_prep_tr(const int* __restrict__ ids,
                                                 const int* __restrict__ tids,
                                                 const float* __restrict__ aspect,
                                                 const float* __restrict__ W1,
                                                 float* __restrict__ v_a,
                                                 float* __restrict__ lens,
                                                 unsigned short* __restrict__ w1mt) {
  int bid = blockIdx.x, tid = threadIdx.x;
  if (bid < 576) {
    __shared__ float tile[32][33];
    int bx = bid % 24, by = bid / 24;
    int tx = tid & 31, ty = tid >> 5;
    for (int j = 0; j < 32; j += 8)
      tile[ty + j][tx] = W1[(size_t)(by * 32 + ty + j) * ND + bx * 32 + tx];
    __syncthreads();
    for (int j = 0; j < 32; j += 8)
      w1mt[(size_t)(bx * 32 + ty + j) * ND + by * 32 + tx] = bf16b(tile[tx][ty + j]);
  } else {
    int b = bid - 576;
    __shared__ int red[256];
    __shared__ float sh_inva;
    int cnt = 0;
    for (int j = tid; j < NS; j += 256) cnt += (ids[b * NS + j] != 0);
    red[tid] = cnt;
    __syncthreads();
    for (int s = 128; s > 0; s >>= 1) {
      if (tid < s) red[tid] += red[tid + s];
      __syncthreads();
    }
    if (tid == 0) {
      int mlen = red[0];
      int acnt = 0;
      for (int t = 0; t < NTA; ++t) acnt += (tids[b * NTA + t] != 0);
      lens[b] = (float)mlen;
      lens[64 + b] = 1.0f / (float)mlen;
      float inva = 1.0f / (float)acnt;
      lens[128 + b] = inva;
      sh_inva = inva;
    }
    __syncthreads();
    float inva = sh_inva;
    for (int j = tid; j < ND; j += 256) {
      float s = 0.f;
      for (int t = 0; t < NTA; ++t) s += aspect[((size_t)b * NTA + t) * ND + j];
      v_a[b * ND + j] = s * inva;
    }
  }
}

// ---------- v_s partials + m' = bf16(memory * loc) ----------
// Grid (32,64) = 2048 blocks, 16 rows each (6 waves/SIMD), fully unrolled.
__global__ __launch_bounds__(192) void k_vs_mprime(const float* __restrict__ memory,
                                                   const float* __restrict__ lens,
                                                   float* __restrict__ part_vs,
                                                   unsigned short* __restrict__ mp) {
  int sc = blockIdx.x, b = blockIdx.y, tid = threadIdx.x;
  int d0 = tid * 4;
  float inv_mlen = lens[64 + b];
  float mlenf = lens[b];
  float s0 = 0, s1 = 0, s2 = 0, s3 = 0;
#pragma unroll
  for (int s = 0; s < 16; ++s) {
    int srow = sc * 16 + s;
    size_t row = (size_t)b * NS + srow;
    const float4 v = *(const float4*)(memory + row * ND + d0);
    s0 += v.x; s1 += v.y; s2 += v.z; s3 += v.w;
    float fs = (float)srow;
    float loc = (fs < mlenf) ? 1.0f - fs * inv_mlen : 1.0f;
    uint2 pk;
    pk.x = bfpack2(v.x * loc, v.y * loc);
    pk.y = bfpack2(v.z * loc, v.w * loc);
    *(uint2*)(mp + row * ND + d0) = pk;
  }
  float4 o;
  o.x = s0 * inv_mlen; o.y = s1 * inv_mlen; o.z = s2 * inv_mlen; o.w = s3 * inv_mlen;
  *(float4*)(part_vs + ((size_t)sc * NB + b) * ND + d0) = o;
}

// ---------- v_s = sum of 32 partials ----------
__global__ __launch_bounds__(192) void k_reduce_vs(const float* __restrict__ part_vs,
                                                   float* __restrict__ v_s) {
  int b = blockIdx.x, tid = threadIdx.x;
  int d0 = tid * 4;
  float a0 = 0, a1 = 0, a2 = 0, a3 = 0;
#pragma unroll
  for (int p = 0; p < 32; ++p) {
    const float4 v = *(const float4*)(part_vs + ((size_t)p * NB + b) * ND + d0);
    a0 += v.x; a1 += v.y; a2 += v.z; a3 += v.w;
  }
  float4 o; o.x = a0; o.y = a1; o.z = a2; o.w = a3;
  *(float4*)(v_s + b * ND + d0) = o;
}

// ---------- ctx_part[dc] = partial( [v_a;v_s] @ [W1_a;W1_s] ) ----------
// b-FASTEST grid (64,6,4); plain store.
__global__ __launch_bounds__(128) void k_ctx(const float* __restrict__ W1,
                                             const float* __restrict__ v_a,
                                             const float* __restrict__ v_s,
                                             float* __restrict__ ctx_part) {
  int b = blockIdx.x, et = blockIdx.y, dc = blockIdx.z, tid = threadIdx.x;
  __shared__ float vbuf[384];
  for (int j = tid; j < 384; j += 128) {
    int k = dc * 384 + j;
    vbuf[j] = (k < ND) ? v_a[b * ND + k] : v_s[b * ND + (k - ND)];
  }
  __syncthreads();
  int e = et * 128 + tid;
  float acc = 0.f;
  const float* Wk = W1 + (size_t)(ND + dc * 384) * ND + e;  // rows 768.. of W1 = [W1_a; W1_s]
#pragma unroll 8
  for (int j = 0; j < 384; ++j) acc += vbuf[j] * Wk[(size_t)j * ND];
  ctx_part[((size_t)dc * NB + b) * ND + e] = acc;
}

// ---------- ctx = sum of 4 partials + b1 (pre-folded for the gemm epilogue) ----------
__global__ __launch_bounds__(192) void k_reduce_ctx(const float* __restrict__ ctx_part,
                                                    const float* __restrict__ b1,
                                                    float* __restrict__ ctx) {
  int b = blockIdx.x, tid = threadIdx.x;
  int d0 = tid * 4;
  const float4 bb = *(const float4*)(b1 + d0);
  float a0 = bb.x, a1 = bb.y, a2 = bb.z, a3 = bb.w;
#pragma unroll
  for (int p = 0; p < 4; ++p) {
    const float4 v = *(const float4*)(ctx_part + ((size_t)p * NB + b) * ND + d0);
    a0 += v.x; a1 += v.y; a2 += v.z; a3 += v.w;
  }
  float4 o; o.x = a0; o.y = a1; o.z = a2; o.w = a3;
  *(float4*)(ctx + b * ND + d0) = o;
}

// ---------- big GEMM: sc_part[et*2+wn][row] = sum_e tanh((m'@W1_m)+ctx)*w2 ----------
// Round 15: 128x64 tile, BK=64, 4 waves (2Mx2N: 64-row x 32-col per wave),
// dbuf 48KB -> 3 blocks/CU. Same 128B-row layout + XOR chunk swizzle + 2-phase
// __syncthreads loop as the measured-63us build. Grid 3072 (et<12 fastest),
// XCD swizzle (3072%8==0, 384/XCD).
__global__ __launch_bounds__(256) void k_gemm_scores(const unsigned short* __restrict__ mp,
                                                     const unsigned short* __restrict__ w1mt,
                                                     const float* __restrict__ ctx,
                                                     const float* __restrict__ w2,
                                                     float* __restrict__ sc_part) {
  __shared__ char lds[49152];
  const int tid = threadIdx.x;
  const int wave = tid >> 6, lane = tid & 63;
  const int bid = blockIdx.x;
  const int swz = (bid & 7) * 384 + (bid >> 3);
  const int rt = swz / 12;          // M-tile (slow)
  const int et = swz - rt * 12;     // N-tile (fast: same-A blocks adjacent)
  const int row0 = rt * 128, n0 = et * 64;
  const int b = row0 >> 9;  // 128 | 512: tile never crosses a batch
  const int wm = wave & 1, wn = wave >> 1;

  // staging: each issue = 64 lanes x 16B = 8 rows x 8 chunks (128B rows)
  const int lrow = lane >> 3;                 // 0..7 row within issue
  const int qlog = (lane & 7) ^ lrow;         // logical chunk for this phys slot
  const char* Abase = (const char*)mp + (size_t)(row0 + lrow) * (ND * 2) + qlog * 16;
  const char* Bbase = (const char*)w1mt + (size_t)(n0 + lrow) * (ND * 2) + qlog * 16;

  f32x4 acc[4][2];
#pragma unroll
  for (int i = 0; i < 4; ++i)
#pragma unroll
    for (int t = 0; t < 2; ++t) acc[i][t] = (f32x4){0.f, 0.f, 0.f, 0.f};

  const int q2 = lane >> 4, c = lane & 15;
  int offA[4][2], offB[2][2];
#pragma unroll
  for (int i = 0; i < 4; ++i) {
    int ml = wm * 64 + i * 16 + c;
    offA[i][0] = ml * 128 + ((q2 ^ (ml & 7)) * 16);
    offA[i][1] = ml * 128 + (((4 + q2) ^ (ml & 7)) * 16);
  }
#pragma unroll
  for (int t = 0; t < 2; ++t) {
    int nl = wn * 32 + t * 16 + c;
    offB[t][0] = nl * 128 + ((q2 ^ (nl & 7)) * 16);
    offB[t][1] = nl * 128 + (((4 + q2) ^ (nl & 7)) * 16);
  }

  auto stage = [&](int bufsel, int kb) {
    char* lA = lds + bufsel * 24576;          // 16KB A + 8KB B per buffer
    char* lB = lA + 16384;
#pragma unroll
    for (int i = 0; i < 4; ++i) {             // A: 16 issues = 128 rows
      int g = wave * 4 + i;
      async_copy16(Abase + (size_t)g * 8 * (ND * 2) + kb, lA + g * 1024);
    }
#pragma unroll
    for (int i = 0; i < 2; ++i) {             // B: 8 issues = 64 rows
      int g = wave * 2 + i;
      async_copy16(Bbase + (size_t)g * 8 * (ND * 2) + kb, lB + g * 1024);
    }
  };

  // prologue: fill buffer 0
  stage(0, 0);
  __syncthreads();

  int cur = 0;
#pragma unroll 2
  for (int t = 0; t < 12; ++t) {  // 12 K-steps of 64 k (128 B/row)
    if (t < 11) stage(cur ^ 1, (t + 1) * 128);  // prefetch next tile (in flight over MFMA)
    const char* lA = lds + cur * 24576;
    const char* lB = lA + 16384;
    bf16x8 af[2][4], bfr[2][2];
#pragma unroll
    for (int kk = 0; kk < 2; ++kk) {
#pragma unroll
      for (int i = 0; i < 4; ++i) af[kk][i] = *(const bf16x8*)(lA + offA[i][kk]);
#pragma unroll
      for (int t2 = 0; t2 < 2; ++t2) bfr[kk][t2] = *(const bf16x8*)(lB + offB[t2][kk]);
    }
#pragma unroll
    for (int kk = 0; kk < 2; ++kk)
#pragma unroll
      for (int i = 0; i < 4; ++i)
#pragma unroll
        for (int t2 = 0; t2 < 2; ++t2)
          acc[i][t2] = __builtin_amdgcn_mfma_f32_16x16x32_bf16(af[kk][i], bfr[kk][t2], acc[i][t2], 0, 0, 0);
    __syncthreads();
    cur ^= 1;
  }

  // epilogue: C/D layout row = q2*4+r, col = c
  float ctxv[2], w2v[2];
#pragma unroll
  for (int t = 0; t < 2; ++t) {
    int n = n0 + wn * 32 + t * 16 + c;
    ctxv[t] = ctx[b * ND + n];
    w2v[t] = w2[n];
  }
  float* scp = sc_part + (size_t)(et * 2 + wn) * (NB * NS);
#pragma unroll
  for (int i = 0; i < 4; ++i) {
#pragma unroll
    for (int r = 0; r < 4; ++r) {
      float s = 0.f;
#pragma unroll
      for (int t = 0; t < 2; ++t) s += fast_tanh(acc[i][t][r] + ctxv[t]) * w2v[t];
      s += __shfl_xor(s, 1, 64);
      s += __shfl_xor(s, 2, 64);
      s += __shfl_xor(s, 4, 64);
      s += __shfl_xor(s, 8, 64);
      if (c == 0) scp[row0 + wm * 64 + i * 16 + q2 * 4 + r] = s;
    }
  }
}

// ---------- softmax: fold 24 score partials ONCE -> alpha ----------
__global__ __launch_bounds__(512) void k_softmax(const float* __restrict__ sc_part,
                                                 float* __restrict__ alpha) {
  int b = blockIdx.x, tid = threadIdx.x;
  int wid = tid >> 6, lane = tid & 63;
  __shared__ float red[8], red2[8];
  float v = 0.f;
#pragma unroll
  for (int p = 0; p < 24; ++p) v += sc_part[(size_t)p * (NB * NS) + b * NS + tid];
  float m = v;
  for (int off = 1; off < 64; off <<= 1) m = fmaxf(m, __shfl_xor(m, off, 64));
  if (lane == 0) red[wid] = m;
  __syncthreads();
  if (tid == 0) {
    float mm = red[0];
    for (int i = 1; i < 8; ++i) mm = fmaxf(mm, red[i]);
    red[0] = mm;
  }
  __syncthreads();
  float M = red[0];
  float e = __expf(v - M);
  float s = e;
  for (int off = 1; off < 64; off <<= 1) s += __shfl_xor(s, off, 64);
  if (lane == 0) red2[wid] = s;
  __syncthreads();
  if (tid == 0) {
    float ss = 0.f;
    for (int i = 0; i < 8; ++i) ss += red2[i];
    red2[0] = ss;
  }
  __syncthreads();
  alpha[b * NS + tid] = e / red2[0];
}

// ---------- v_ts partials: pure stream of alpha + mp ----------
__global__ __launch_bounds__(192) void k_vts(const unsigned short* __restrict__ mp,
                                             const float* __restrict__ alpha,
                                             float* __restrict__ part_vts) {
  int sc = blockIdx.x, b = blockIdx.y, tid = threadIdx.x;
  __shared__ float al[32];
  if (tid < 32) al[tid] = alpha[b * NS + sc * 32 + tid];
  __syncthreads();
  int d0 = tid * 4;
  float a0 = 0, a1 = 0, a2 = 0, a3 = 0;
#pragma unroll 8
  for (int s = 0; s < 32; ++s) {
    size_t row = (size_t)b * NS + sc * 32 + s;
    uint2 pk = *(const uint2*)(mp + row * ND + d0);
    float a = al[s];
    a0 += a * __uint_as_float(pk.x << 16);
    a1 += a * __uint_as_float(pk.x & 0xFFFF0000u);
    a2 += a * __uint_as_float(pk.y << 16);
    a3 += a * __uint_as_float(pk.y & 0xFFFF0000u);
  }
  float4 o; o.x = a0; o.y = a1; o.z = a2; o.w = a3;
  *(float4*)(part_vts + ((size_t)sc * NB + b) * ND + d0) = o;
}

// ---------- u_part[dc] = partial( (v_ts+v_s) @ Wm ) ----------
// b-FASTEST (64,6,4); v_ts folded from 16 partials (L2-resident); plain store.
__global__ __launch_bounds__(128) void k_final1(const float* __restrict__ part_vts,
                                                const float* __restrict__ v_s,
                                                const float* __restrict__ Wm,
                                                float* __restrict__ u_part) {
  int b = blockIdx.x, et = blockIdx.y, dc = blockIdx.z, tid = threadIdx.x;
  __shared__ float vbuf[192];
  for (int j = tid; j < 192; j += 128) {
    int d = dc * 192 + j;
    float v = v_s[b * ND + d];
#pragma unroll
    for (int p = 0; p < 16; ++p) v += part_vts[((size_t)p * NB + b) * ND + d];
    vbuf[j] = v;
  }
  __syncthreads();
  int e = et * 128 + tid;
  float acc = 0.f;
  const float* Wk = Wm + (size_t)(dc * 192) * ND + e;
#pragma unroll 8
  for (int j = 0; j < 192; ++j) acc += vbuf[j] * Wk[(size_t)j * ND];
  u_part[((size_t)dc * NB + b) * ND + e] = acc;
}

// ---------- logits = tanh(sum u_part + bm) @ Wd + bd ----------
__global__ __launch_bounds__(256) void k_final2(const float* __restrict__ u_part,
                                                const float* __restrict__ bm,
                                                const float* __restrict__ Wd,
                                                const float* __restrict__ bd,
                                                float* __restrict__ out) {
  int b = blockIdx.x, tid = threadIdx.x;
  int wid = tid >> 6, lane = tid & 63;
  __shared__ float red[4][3];
  float p0 = 0, p1 = 0, p2 = 0;
  for (int e = tid; e < ND; e += 256) {
    float uv = bm[e];
#pragma unroll
    for (int dc = 0; dc < 4; ++dc) uv += u_part[((size_t)dc * NB + b) * ND + e];
    float vm = fast_tanh(uv);
    p0 += vm * Wd[e * 3 + 0];
    p1 += vm * Wd[e * 3 + 1];
    p2 += vm * Wd[e * 3 + 2];
  }
  for (int off = 1; off < 64; off <<= 1) {
    p0 += __shfl_xor(p0, off, 64);
    p1 += __shfl_xor(p1, off, 64);
    p2 += __shfl_xor(p2, off, 64);
  }
  if (lane == 0) { red[wid][0] = p0; red[wid][1] = p1; red[wid][2] = p2; }
  __syncthreads();
  if (tid == 0) {
    out[b * 3 + 0] = red[0][0] + red[1][0] + red[2][0] + red[3][0] + bd[0];
    out[b * 3 + 1] = red[0][1] + red[1][1] + red[2][1] + red[3][1] + bd[1];
    out[b * 3 + 2] = red[0][2] + red[1][2] + red[2][2] + red[3][2] + bd[2];
  }
}

extern "C" void kernel_launch(void* const* d_in, const int* in_sizes, int n_in,
                              void* d_out, int out_size, void* d_ws, size_t ws_size,
                              hipStream_t stream) {
  const float* memory = (const float*)d_in[0];
  const float* aspect = (const float*)d_in[1];
  const int* ids = (const int*)d_in[2];
  const int* tids = (const int*)d_in[3];
  const float* W1 = (const float*)d_in[4];
  const float* b1 = (const float*)d_in[5];
  const float* w2 = (const float*)d_in[6];
  const float* Wm = (const float*)d_in[7];
  const float* bm = (const float*)d_in[8];
  const float* Wd = (const float*)d_in[9];
  const float* bd = (const float*)d_in[10];
  float* out = (float*)d_out;

  char* ws = (char*)d_ws;
  float* part_vs = (float*)(ws + OFF_PVS);
  float* part_vts = (float*)(ws + OFF_PVTS);
  float* ctx_part = (float*)(ws + OFF_PCTX);
  float* ctx = (float*)(ws + OFF_CTX);
  float* u_part = (float*)(ws + OFF_PU);
  float* sc_part = (float*)(ws + OFF_PSC);
  float* alpha = (float*)(ws + OFF_ALPHA);
  float* v_s = (float*)(ws + OFF_VS);
  float* v_a = (float*)(ws + OFF_VA);
  float* lens = (float*)(ws + OFF_LENS);
  unsigned short* w1mt = (unsigned short*)(ws + OFF_W1MT);
  unsigned short* mp = (unsigned short*)(ws + OFF_MP);

  // no memset: every workspace buffer is fully written before it is read.

  k_prep_tr<<<640, 256, 0, stream>>>(ids, tids, aspect, W1, v_a, lens, w1mt);
  k_vs_mprime<<<dim3(32, NB), 192, 0, stream>>>(memory, lens, part_vs, mp);
  k_reduce_vs<<<NB, 192, 0, stream>>>(part_vs, v_s);
  k_ctx<<<dim3(64, 6, 4), 128, 0, stream>>>(W1, v_a, v_s, ctx_part);
  k_reduce_ctx<<<NB, 192, 0, stream>>>(ctx_part, b1, ctx);
  k_gemm_scores<<<3072, 256, 0, stream>>>(mp, w1mt, ctx, w2, sc_part);
  k_softmax<<<NB, 512, 0, stream>>>(sc_part, alpha);
  k_vts<<<dim3(16, NB), 192, 0, stream>>>(mp, alpha, part_vts);
  k_final1<<<dim3(64, 6, 4), 128, 0, stream>>>(part_vts, v_s, Wm, u_part);
  k_final2<<<NB, 256, 0, stream>>>(u_part, bm, Wd, bd, out);
}

// Round 14
// 300.952 us; speedup vs baseline: 1.0372x; 1.0372x over previous
//
#include <hip/hip_runtime.h>
#include <hip/hip_bf16.h>

// Cabasc: B=64, S=512, Ta=8, D=768
// Round 16: gemm rebuilt as 256x128 tile, 8 waves (512 thr), TRI-buffered LDS
//   (3 x 48KB = 144KB), ONE raw barrier + ONE counted vmcnt(6) per K-step:
//   stage(t+2) issued at iter top, end-of-iter vmcnt drains only t+1 (t+2
//   stays in flight across the barrier). Per-wave geometry/offsets/epilogue
//   identical to the proven 65us kernel (64x64 out, XOR swizzle, 0 conflicts).
//   R13 falsified occupancy lever (71us); 128-wide scheduling space exhausted
//   (2ph=65, cnt-vmcnt=82x2, 128x64=71) -> wide-tile regime is the one
//   measured escape (learn_hip 256-class: 1563 TF).
//   All other kernels + workspace byte-frozen from R12 (303.5us, passed);
//   sc_part stays 12 partials (et*2+wn) so softmax is unchanged.

#define NB 64
#define NS 512
#define ND 768
#define NTA 8

typedef __attribute__((ext_vector_type(8))) __bf16 bf16x8;
typedef __attribute__((ext_vector_type(4))) float f32x4;

// ---- workspace layout (bytes), all buffers fully written before read ----
#define OFF_PVS 0u              // part_vs  [32][NB][ND] f32 = 6291456
#define OFF_PVTS 6291456u       // part_vts [16][NB][ND] f32 = 3145728
#define OFF_PCTX 9437184u       // ctx_part [4][NB][ND] f32  = 786432
#define OFF_CTX 10223616u       // ctx      [NB][ND] f32     = 196608 (b1 folded)
#define OFF_PU 10420224u        // u_part   [4][NB][ND] f32  = 786432
#define OFF_PSC 11206656u       // sc_part  [12][NB][NS] f32 = 1572864
#define OFF_ALPHA 12779520u     // alpha    [NB][NS] f32     = 131072
#define OFF_VS 12910592u        // v_s  NB*ND f32 = 196608
#define OFF_VA 13107200u        // v_a  NB*ND f32 = 196608
#define OFF_LENS 13303808u      // mlenf[64] | inv_mlen[64] | inv_alen[64]
#define OFF_W1MT 13304832u      // ND*ND bf16 = 1179648
#define OFF_MP 14484480u        // NB*NS*ND bf16 = 50331648 (total ~64.8 MB)

__device__ __forceinline__ float fast_tanh(float x) {
  x = fminf(fmaxf(x, -15.f), 15.f);
  float t = __expf(2.f * x);
  return __fdividef(t - 1.f, t + 1.f);
}

__device__ __forceinline__ unsigned bfpack2(float a, float b) {
  unsigned ua = __float_as_uint(a), ub = __float_as_uint(b);
  ua = (ua + 0x7FFFu + ((ua >> 16) & 1u)) >> 16;
  ub = (ub + 0x7FFFu + ((ub >> 16) & 1u)) >> 16;
  return ua | (ub << 16);
}

__device__ __forceinline__ unsigned short bf16b(float f) {
  unsigned u = __float_as_uint(f);
  u = (u + 0x7FFFu + ((u >> 16) & 1u)) >> 16;
  return (unsigned short)u;
}

__device__ __forceinline__ void async_copy16(const void* g, void* l) {
  __builtin_amdgcn_global_load_lds(
      (const __attribute__((address_space(1))) void*)g,
      (__attribute__((address_space(3))) void*)l, 16, 0, 0);
}

// ---------- fused: W1_m transpose (blocks 0..575) + lens/v_a prep (blocks 576..639) ----------
__global__ __launch_bounds__(256) void k_prep_tr(const int* __restrict__ ids,
                                                 const int* __restrict__ tids,
                                                 const float* __restrict__ aspect,
                                                 const float* __restrict__ W1,
                                                 float* __restrict__ v_a,
                                                 float* __restrict__ lens,
                                                 unsigned short* __restrict__ w1mt) {
  int bid = blockIdx.x, tid = threadIdx.x;
  if (bid < 576) {
    __shared__ float tile[32][33];
    int bx = bid % 24, by = bid / 24;
    int tx = tid & 31, ty = tid >> 5;
    for (int j = 0; j < 32; j += 8)
      tile[ty + j][tx] = W1[(size_t)(by * 32 + ty + j) * ND + bx * 32 + tx];
    __syncthreads();
    for (int j = 0; j < 32; j += 8)
      w1mt[(size_t)(bx * 32 + ty + j) * ND + by * 32 + tx] = bf16b(tile[tx][ty + j]);
  } else {
    int b = bid - 576;
    __shared__ int red[256];
    __shared__ float sh_inva;
    int cnt = 0;
    for (int j = tid; j < NS; j += 256) cnt += (ids[b * NS + j] != 0);
    red[tid] = cnt;
    __syncthreads();
    for (int s = 128; s > 0; s >>= 1) {
      if (tid < s) red[tid] += red[tid + s];
      __syncthreads();
    }
    if (tid == 0) {
      int mlen = red[0];
      int acnt = 0;
      for (int t = 0; t < NTA; ++t) acnt += (tids[b * NTA + t] != 0);
      lens[b] = (float)mlen;
      lens[64 + b] = 1.0f / (float)mlen;
      float inva = 1.0f / (float)acnt;
      lens[128 + b] = inva;
      sh_inva = inva;
    }
    __syncthreads();
    float inva = sh_inva;
    for (int j = tid; j < ND; j += 256) {
      float s = 0.f;
      for (int t = 0; t < NTA; ++t) s += aspect[((size_t)b * NTA + t) * ND + j];
      v_a[b * ND + j] = s * inva;
    }
  }
}

// ---------- v_s partials + m' = bf16(memory * loc) ----------
// Grid (32,64) = 2048 blocks, 16 rows each (6 waves/SIMD), fully unrolled.
__global__ __launch_bounds__(192) void k_vs_mprime(const float* __restrict__ memory,
                                                   const float* __restrict__ lens,
                                                   float* __restrict__ part_vs,
                                                   unsigned short* __restrict__ mp) {
  int sc = blockIdx.x, b = blockIdx.y, tid = threadIdx.x;
  int d0 = tid * 4;
  float inv_mlen = lens[64 + b];
  float mlenf = lens[b];
  float s0 = 0, s1 = 0, s2 = 0, s3 = 0;
#pragma unroll
  for (int s = 0; s < 16; ++s) {
    int srow = sc * 16 + s;
    size_t row = (size_t)b * NS + srow;
    const float4 v = *(const float4*)(memory + row * ND + d0);
    s0 += v.x; s1 += v.y; s2 += v.z; s3 += v.w;
    float fs = (float)srow;
    float loc = (fs < mlenf) ? 1.0f - fs * inv_mlen : 1.0f;
    uint2 pk;
    pk.x = bfpack2(v.x * loc, v.y * loc);
    pk.y = bfpack2(v.z * loc, v.w * loc);
    *(uint2*)(mp + row * ND + d0) = pk;
  }
  float4 o;
  o.x = s0 * inv_mlen; o.y = s1 * inv_mlen; o.z = s2 * inv_mlen; o.w = s3 * inv_mlen;
  *(float4*)(part_vs + ((size_t)sc * NB + b) * ND + d0) = o;
}

// ---------- v_s = sum of 32 partials ----------
__global__ __launch_bounds__(192) void k_reduce_vs(const float* __restrict__ part_vs,
                                                   float* __restrict__ v_s) {
  int b = blockIdx.x, tid = threadIdx.x;
  int d0 = tid * 4;
  float a0 = 0, a1 = 0, a2 = 0, a3 = 0;
#pragma unroll
  for (int p = 0; p < 32; ++p) {
    const float4 v = *(const float4*)(part_vs + ((size_t)p * NB + b) * ND + d0);
    a0 += v.x; a1 += v.y; a2 += v.z; a3 += v.w;
  }
  float4 o; o.x = a0; o.y = a1; o.z = a2; o.w = a3;
  *(float4*)(v_s + b * ND + d0) = o;
}

// ---------- ctx_part[dc] = partial( [v_a;v_s] @ [W1_a;W1_s] ) ----------
// b-FASTEST grid (64,6,4); plain store.
__global__ __launch_bounds__(128) void k_ctx(const float* __restrict__ W1,
                                             const float* __restrict__ v_a,
                                             const float* __restrict__ v_s,
                                             float* __restrict__ ctx_part) {
  int b = blockIdx.x, et = blockIdx.y, dc = blockIdx.z, tid = threadIdx.x;
  __shared__ float vbuf[384];
  for (int j = tid; j < 384; j += 128) {
    int k = dc * 384 + j;
    vbuf[j] = (k < ND) ? v_a[b * ND + k] : v_s[b * ND + (k - ND)];
  }
  __syncthreads();
  int e = et * 128 + tid;
  float acc = 0.f;
  const float* Wk = W1 + (size_t)(ND + dc * 384) * ND + e;  // rows 768.. of W1 = [W1_a; W1_s]
#pragma unroll 8
  for (int j = 0; j < 384; ++j) acc += vbuf[j] * Wk[(size_t)j * ND];
  ctx_part[((size_t)dc * NB + b) * ND + e] = acc;
}

// ---------- ctx = sum of 4 partials + b1 (pre-folded for the gemm epilogue) ----------
__global__ __launch_bounds__(192) void k_reduce_ctx(const float* __restrict__ ctx_part,
                                                    const float* __restrict__ b1,
                                                    float* __restrict__ ctx) {
  int b = blockIdx.x, tid = threadIdx.x;
  int d0 = tid * 4;
  const float4 bb = *(const float4*)(b1 + d0);
  float a0 = bb.x, a1 = bb.y, a2 = bb.z, a3 = bb.w;
#pragma unroll
  for (int p = 0; p < 4; ++p) {
    const float4 v = *(const float4*)(ctx_part + ((size_t)p * NB + b) * ND + d0);
    a0 += v.x; a1 += v.y; a2 += v.z; a3 += v.w;
  }
  float4 o; o.x = a0; o.y = a1; o.z = a2; o.w = a3;
  *(float4*)(ctx + b * ND + d0) = o;
}

// ---------- big GEMM: sc_part[et*2+wn][row] = sum_e tanh((m'@W1_m)+ctx)*w2 ----------
// Round 16: 256x128 tile, BK=64, 8 waves (4M x 2N, 64x64 out each), TRI-buffer
// LDS 3 x (32KB A + 16KB B) = 144KB, 1 block/CU. Pipeline: stage(t+2) at iter
// top; end-of-iter s_waitcnt vmcnt(6) drains only t+1's 6 issues (t+2 flies
// across the barrier); ONE s_barrier per K-step. Slot reuse safe: a slot's
// ds_reads are consumed by MFMA (in-order DS completion) before the barrier
// that precedes the overwriting stage. Grid 768 = 3 exact CU rounds; XCD
// swizzle (768%8==0, 96/XCD), et-fastest.
__global__ __launch_bounds__(512) void k_gemm_scores(const unsigned short* __restrict__ mp,
                                                     const unsigned short* __restrict__ w1mt,
                                                     const float* __restrict__ ctx,
                                                     const float* __restrict__ w2,
                                                     float* __restrict__ sc_part) {
  __shared__ char lds[147456];
  const int tid = threadIdx.x;
  const int wave = tid >> 6, lane = tid & 63;
  const int bid = blockIdx.x;
  const int swz = (bid & 7) * 96 + (bid >> 3);
  const int rt = swz / 6;           // M-tile (slow), 0..127
  const int et = swz - rt * 6;      // N-tile (fast: same-A blocks adjacent)
  const int row0 = rt * 256, n0 = et * 128;
  const int b = row0 >> 9;  // 256 | 512: tile never crosses a batch
  const int wm = wave & 3, wn = wave >> 2;

  // staging: each issue = 64 lanes x 16B = 8 rows x 8 chunks (128B rows)
  const int lrow = lane >> 3;                 // 0..7 row within issue
  const int qlog = (lane & 7) ^ lrow;         // logical chunk for this phys slot
  const char* Abase = (const char*)mp + (size_t)(row0 + lrow) * (ND * 2) + qlog * 16;
  const char* Bbase = (const char*)w1mt + (size_t)(n0 + lrow) * (ND * 2) + qlog * 16;

  f32x4 acc[4][4];
#pragma unroll
  for (int i = 0; i < 4; ++i)
#pragma unroll
    for (int t = 0; t < 4; ++t) acc[i][t] = (f32x4){0.f, 0.f, 0.f, 0.f};

  const int q2 = lane >> 4, c = lane & 15;
  int offA[4][2], offB[4][2];
#pragma unroll
  for (int i = 0; i < 4; ++i) {
    int ml = wm * 64 + i * 16 + c;            // 0..255
    offA[i][0] = ml * 128 + ((q2 ^ (ml & 7)) * 16);
    offA[i][1] = ml * 128 + (((4 + q2) ^ (ml & 7)) * 16);
  }
#pragma unroll
  for (int t = 0; t < 4; ++t) {
    int nl = wn * 64 + t * 16 + c;            // 0..127
    offB[t][0] = nl * 128 + ((q2 ^ (nl & 7)) * 16);
    offB[t][1] = nl * 128 + (((4 + q2) ^ (nl & 7)) * 16);
  }

  auto stage = [&](int slot, int kb) {
    char* lA = lds + slot * 49152;            // 32KB A + 16KB B per slot
    char* lB = lA + 32768;
#pragma unroll
    for (int i = 0; i < 4; ++i) {             // A: 32 issues = 256 rows
      int g = wave * 4 + i;
      async_copy16(Abase + (size_t)g * 8 * (ND * 2) + kb, lA + g * 1024);
    }
#pragma unroll
    for (int i = 0; i < 2; ++i) {             // B: 16 issues = 128 rows
      int g = wave * 2 + i;
      async_copy16(Bbase + (size_t)g * 8 * (ND * 2) + kb, lB + g * 1024);
    }
  };

  // prologue: tiles 0,1 in flight (12 issues/wave); wait tile 0 (oldest 6)
  stage(0, 0);
  stage(1, 128);
  asm volatile("s_waitcnt vmcnt(6)" ::: "memory");
  __builtin_amdgcn_s_barrier();

#pragma unroll
  for (int u = 0; u < 12; ++u) {  // 12 K-steps of 64 k (128 B/row)
    if (u + 2 < 12) stage((u + 2) % 3, (u + 2) * 128);  // depth-2 in flight
    const char* lA = lds + (u % 3) * 49152;
    const char* lB = lA + 32768;
    bf16x8 af[2][4], bfr[2][4];
#pragma unroll
    for (int kk = 0; kk < 2; ++kk) {
#pragma unroll
      for (int i = 0; i < 4; ++i) af[kk][i] = *(const bf16x8*)(lA + offA[i][kk]);
#pragma unroll
      for (int t2 = 0; t2 < 4; ++t2) bfr[kk][t2] = *(const bf16x8*)(lB + offB[t2][kk]);
    }
    __builtin_amdgcn_s_setprio(1);
#pragma unroll
    for (int kk = 0; kk < 2; ++kk)
#pragma unroll
      for (int i = 0; i < 4; ++i)
#pragma unroll
        for (int t2 = 0; t2 < 4; ++t2)
          acc[i][t2] = __builtin_amdgcn_mfma_f32_16x16x32_bf16(af[kk][i], bfr[kk][t2], acc[i][t2], 0, 0, 0);
    __builtin_amdgcn_s_setprio(0);
    // drain only tile u+1's loads (6/wave); tile u+2's 6 stay in flight
    if (u < 10)      { asm volatile("s_waitcnt vmcnt(6)" ::: "memory"); }
    else if (u == 10){ asm volatile("s_waitcnt vmcnt(0)" ::: "memory"); }
    if (u < 11) __builtin_amdgcn_s_barrier();
  }

  // epilogue: C/D layout row = q2*4+r, col = c
  float ctxv[4], w2v[4];
#pragma unroll
  for (int t = 0; t < 4; ++t) {
    int n = n0 + wn * 64 + t * 16 + c;
    ctxv[t] = ctx[b * ND + n];
    w2v[t] = w2[n];
  }
  float* scp = sc_part + (size_t)(et * 2 + wn) * (NB * NS);
#pragma unroll
  for (int i = 0; i < 4; ++i) {
#pragma unroll
    for (int r = 0; r < 4; ++r) {
      float s = 0.f;
#pragma unroll
      for (int t = 0; t < 4; ++t) s += fast_tanh(acc[i][t][r] + ctxv[t]) * w2v[t];
      s += __shfl_xor(s, 1, 64);
      s += __shfl_xor(s, 2, 64);
      s += __shfl_xor(s, 4, 64);
      s += __shfl_xor(s, 8, 64);
      if (c == 0) scp[row0 + wm * 64 + i * 16 + q2 * 4 + r] = s;
    }
  }
}

// ---------- softmax: fold 12 score partials ONCE -> alpha ----------
__global__ __launch_bounds__(512) void k_softmax(const float* __restrict__ sc_part,
                                                 float* __restrict__ alpha) {
  int b = blockIdx.x, tid = threadIdx.x;
  int wid = tid >> 6, lane = tid & 63;
  __shared__ float red[8], red2[8];
  float v = 0.f;
#pragma unroll
  for (int p = 0; p < 12; ++p) v += sc_part[(size_t)p * (NB * NS) + b * NS + tid];
  float m = v;
  for (int off = 1; off < 64; off <<= 1) m = fmaxf(m, __shfl_xor(m, off, 64));
  if (lane == 0) red[wid] = m;
  __syncthreads();
  if (tid == 0) {
    float mm = red[0];
    for (int i = 1; i < 8; ++i) mm = fmaxf(mm, red[i]);
    red[0] = mm;
  }
  __syncthreads();
  float M = red[0];
  float e = __expf(v - M);
  float s = e;
  for (int off = 1; off < 64; off <<= 1) s += __shfl_xor(s, off, 64);
  if (lane == 0) red2[wid] = s;
  __syncthreads();
  if (tid == 0) {
    float ss = 0.f;
    for (int i = 0; i < 8; ++i) ss += red2[i];
    red2[0] = ss;
  }
  __syncthreads();
  alpha[b * NS + tid] = e / red2[0];
}

// ---------- v_ts partials: pure stream of alpha + mp ----------
__global__ __launch_bounds__(192) void k_vts(const unsigned short* __restrict__ mp,
                                             const float* __restrict__ alpha,
                                             float* __restrict__ part_vts) {
  int sc = blockIdx.x, b = blockIdx.y, tid = threadIdx.x;
  __shared__ float al[32];
  if (tid < 32) al[tid] = alpha[b * NS + sc * 32 + tid];
  __syncthreads();
  int d0 = tid * 4;
  float a0 = 0, a1 = 0, a2 = 0, a3 = 0;
#pragma unroll 8
  for (int s = 0; s < 32; ++s) {
    size_t row = (size_t)b * NS + sc * 32 + s;
    uint2 pk = *(const uint2*)(mp + row * ND + d0);
    float a = al[s];
    a0 += a * __uint_as_float(pk.x << 16);
    a1 += a * __uint_as_float(pk.x & 0xFFFF0000u);
    a2 += a * __uint_as_float(pk.y << 16);
    a3 += a * __uint_as_float(pk.y & 0xFFFF0000u);
  }
  float4 o; o.x = a0; o.y = a1; o.z = a2; o.w = a3;
  *(float4*)(part_vts + ((size_t)sc * NB + b) * ND + d0) = o;
}

// ---------- u_part[dc] = partial( (v_ts+v_s) @ Wm ) ----------
// b-FASTEST (64,6,4); v_ts folded from 16 partials (L2-resident); plain store.
__global__ __launch_bounds__(128) void k_final1(const float* __restrict__ part_vts,
                                                const float* __restrict__ v_s,
                                                const float* __restrict__ Wm,
                                                float* __restrict__ u_part) {
  int b = blockIdx.x, et = blockIdx.y, dc = blockIdx.z, tid = threadIdx.x;
  __shared__ float vbuf[192];
  for (int j = tid; j < 192; j += 128) {
    int d = dc * 192 + j;
    float v = v_s[b * ND + d];
#pragma unroll
    for (int p = 0; p < 16; ++p) v += part_vts[((size_t)p * NB + b) * ND + d];
    vbuf[j] = v;
  }
  __syncthreads();
  int e = et * 128 + tid;
  float acc = 0.f;
  const float* Wk = Wm + (size_t)(dc * 192) * ND + e;
#pragma unroll 8
  for (int j = 0; j < 192; ++j) acc += vbuf[j] * Wk[(size_t)j * ND];
  u_part[((size_t)dc * NB + b) * ND + e] = acc;
}

// ---------- logits = tanh(sum u_part + bm) @ Wd + bd ----------
__global__ __launch_bounds__(256) void k_final2(const float* __restrict__ u_part,
                                                const float* __restrict__ bm,
                                                const float* __restrict__ Wd,
                                                const float* __restrict__ bd,
                                                float* __restrict__ out) {
  int b = blockIdx.x, tid = threadIdx.x;
  int wid = tid >> 6, lane = tid & 63;
  __shared__ float red[4][3];
  float p0 = 0, p1 = 0, p2 = 0;
  for (int e = tid; e < ND; e += 256) {
    float uv = bm[e];
#pragma unroll
    for (int dc = 0; dc < 4; ++dc) uv += u_part[((size_t)dc * NB + b) * ND + e];
    float vm = fast_tanh(uv);
    p0 += vm * Wd[e * 3 + 0];
    p1 += vm * Wd[e * 3 + 1];
    p2 += vm * Wd[e * 3 + 2];
  }
  for (int off = 1; off < 64; off <<= 1) {
    p0 += __shfl_xor(p0, off, 64);
    p1 += __shfl_xor(p1, off, 64);
    p2 += __shfl_xor(p2, off, 64);
  }
  if (lane == 0) { red[wid][0] = p0; red[wid][1] = p1; red[wid][2] = p2; }
  __syncthreads();
  if (tid == 0) {
    out[b * 3 + 0] = red[0][0] + red[1][0] + red[2][0] + red[3][0] + bd[0];
    out[b * 3 + 1] = red[0][1] + red[1][1] + red[2][1] + red[3][1] + bd[1];
    out[b * 3 + 2] = red[0][2] + red[1][2] + red[2][2] + red[3][2] + bd[2];
  }
}

extern "C" void kernel_launch(void* const* d_in, const int* in_sizes, int n_in,
                              void* d_out, int out_size, void* d_ws, size_t ws_size,
                              hipStream_t stream) {
  const float* memory = (const float*)d_in[0];
  const float* aspect = (const float*)d_in[1];
  const int* ids = (const int*)d_in[2];
  const int* tids = (const int*)d_in[3];
  const float* W1 = (const float*)d_in[4];
  const float* b1 = (const float*)d_in[5];
  const float* w2 = (const float*)d_in[6];
  const float* Wm = (const float*)d_in[7];
  const float* bm = (const float*)d_in[8];
  const float* Wd = (const float*)d_in[9];
  const float* bd = (const float*)d_in[10];
  float* out = (float*)d_out;

  char* ws = (char*)d_ws;
  float* part_vs = (float*)(ws + OFF_PVS);
  float* part_vts = (float*)(ws + OFF_PVTS);
  float* ctx_part = (float*)(ws + OFF_PCTX);
  float* ctx = (float*)(ws + OFF_CTX);
  float* u_part = (float*)(ws + OFF_PU);
  float* sc_part = (float*)(ws + OFF_PSC);
  float* alpha = (float*)(ws + OFF_ALPHA);
  float* v_s = (float*)(ws + OFF_VS);
  float* v_a = (float*)(ws + OFF_VA);
  float* lens = (float*)(ws + OFF_LENS);
  unsigned short* w1mt = (unsigned short*)(ws + OFF_W1MT);
  unsigned short* mp = (unsigned short*)(ws + OFF_MP);

  // no memset: every workspace buffer is fully written before it is read.

  k_prep_tr<<<640, 256, 0, stream>>>(ids, tids, aspect, W1, v_a, lens, w1mt);
  k_vs_mprime<<<dim3(32, NB), 192, 0, stream>>>(memory, lens, part_vs, mp);
  k_reduce_vs<<<NB, 192, 0, stream>>>(part_vs, v_s);
  k_ctx<<<dim3(64, 6, 4), 128, 0, stream>>>(W1, v_a, v_s, ctx_part);
  k_reduce_ctx<<<NB, 192, 0, stream>>>(ctx_part, b1, ctx);
  k_gemm_scores<<<768, 512, 0, stream>>>(mp, w1mt, ctx, w2, sc_part);
  k_softmax<<<NB, 512, 0, stream>>>(sc_part, alpha);
  k_vts<<<dim3(16, NB), 192, 0, stream>>>(mp, alpha, part_vts);
  k_final1<<<dim3(64, 6, 4), 128, 0, stream>>>(part_vts, v_s, Wm, u_part);
  k_final2<<<NB, 256, 0, stream>>>(u_part, bm, Wd, bd, out);
}